// Round 4
// baseline (144.054 us; speedup 1.0000x reference)
//
#include <hip/hip_runtime.h>

// BPMLL loss, B=16384 rows, L=1024 cols, f32 in, scalar f32 out.
// Per row: pos = sum y*exp(-c); neg = sum (1-y)*exp(c);
// loss = pos*neg/(sum_y*(L-sum_y)); out = mean over rows.
//
// R1/R2: ~43us @ ~3.05 TB/s combined (65MB HBM + ~65MB L3-resident from the
// harness's input restore). VGPR=44 proved the machine scheduler interleaves
// load/consume (~4 loads in flight). R3 inline-asm attempt failed to compile
// (tied 128-bit asm operands unsupported).
// This version: plain loads + __builtin_amdgcn_sched_barrier(0) between the
// 16-load cluster and consumption. Loads stay clustered (16KB in flight per
// wave); backend still inserts correct fine-grained vmcnt waits before uses.

#define NROWS 16384
#define NCOLS 1024
#define WPB 4
#define NBLOCKS 2048              // 8 rows/block, 2 rows/wave, no tail

__device__ __forceinline__ void elem(float cv, int yv,
                                     float& pos, float& neg, float& cnt) {
    float t = __expf(yv ? -cv : cv);   // one transcendental per element
    pos += yv ? t : 0.f;
    neg += yv ? 0.f : t;
    cnt += (float)yv;
}

__device__ __forceinline__ void consume4(const float4& cv, const int4& yv,
                                         float& pos, float& neg, float& cnt) {
    elem(cv.x, yv.x, pos, neg, cnt);
    elem(cv.y, yv.y, pos, neg, cnt);
    elem(cv.z, yv.z, pos, neg, cnt);
    elem(cv.w, yv.w, pos, neg, cnt);
}

__device__ __forceinline__ float row_finish(float pos, float neg, float cnt) {
#pragma unroll
    for (int off = 1; off < 64; off <<= 1) {
        pos += __shfl_xor(pos, off);
        neg += __shfl_xor(neg, off);
        cnt += __shfl_xor(cnt, off);
    }
    return (pos * neg) / (cnt * ((float)NCOLS - cnt));  // BIAS=(1,1)
}

__global__ __launch_bounds__(256, 4) void bpmll_rows_kernel(
    const float* __restrict__ c, const int* __restrict__ y,
    float* __restrict__ partials) {
    const int wave = threadIdx.x >> 6;
    const int lane = threadIdx.x & 63;
    const int row0 = (blockIdx.x * WPB + wave) * 2;  // 2 rows per wave

    const float4* __restrict__ cA = (const float4*)(c + (size_t)row0 * NCOLS);
    const float4* __restrict__ cB = cA + NCOLS / 4;
    const int4* __restrict__ yA = (const int4*)(y + (size_t)row0 * NCOLS);
    const int4* __restrict__ yB = yA + NCOLS / 4;

    // Issue ALL 16 loads (2 rows x (4 c4 + 4 y4)); sched_barrier(0) forbids
    // the scheduler from sinking consumption into the load cluster.
    float4 ca[4], cb[4];
    int4 ya[4], yb[4];
#pragma unroll
    for (int i = 0; i < 4; ++i) ca[i] = cA[lane + 64 * i];
#pragma unroll
    for (int i = 0; i < 4; ++i) ya[i] = yA[lane + 64 * i];
#pragma unroll
    for (int i = 0; i < 4; ++i) cb[i] = cB[lane + 64 * i];
#pragma unroll
    for (int i = 0; i < 4; ++i) yb[i] = yB[lane + 64 * i];

    __builtin_amdgcn_sched_barrier(0);   // nothing crosses: 16 loads in flight

    float posA = 0.f, negA = 0.f, cntA = 0.f;
#pragma unroll
    for (int i = 0; i < 4; ++i) consume4(ca[i], ya[i], posA, negA, cntA);
    float lossA = row_finish(posA, negA, cntA);

    float posB = 0.f, negB = 0.f, cntB = 0.f;
#pragma unroll
    for (int i = 0; i < 4; ++i) consume4(cb[i], yb[i], posB, negB, cntB);
    float lossB = row_finish(posB, negB, cntB);

    __shared__ float acc[WPB];
    if (lane == 0) acc[wave] = lossA + lossB;
    __syncthreads();
    if (threadIdx.x == 0) {
        partials[blockIdx.x] =
            (acc[0] + acc[1] + acc[2] + acc[3]) * (1.0f / (float)NROWS);
    }
}

__global__ __launch_bounds__(256) void bpmll_reduce_kernel(
    const float* __restrict__ partials, float* __restrict__ out) {
    // 2048 partials, 256 threads -> two float4 per thread.
    float4 v0 = ((const float4*)partials)[threadIdx.x];
    float4 v1 = ((const float4*)partials)[threadIdx.x + 256];
    float s = (v0.x + v0.y + v0.z + v0.w) + (v1.x + v1.y + v1.z + v1.w);
#pragma unroll
    for (int off = 1; off < 64; off <<= 1) s += __shfl_xor(s, off);

    __shared__ float smem[4];
    const int lane = threadIdx.x & 63;
    const int wave = threadIdx.x >> 6;
    if (lane == 0) smem[wave] = s;
    __syncthreads();
    if (threadIdx.x == 0) out[0] = smem[0] + smem[1] + smem[2] + smem[3];
}

extern "C" void kernel_launch(void* const* d_in, const int* in_sizes, int n_in,
                              void* d_out, int out_size, void* d_ws, size_t ws_size,
                              hipStream_t stream) {
    const float* c = (const float*)d_in[0];
    const int* y = (const int*)d_in[1];
    float* partials = (float*)d_ws;   // NBLOCKS floats = 8 KiB scratch
    float* out = (float*)d_out;

    bpmll_rows_kernel<<<NBLOCKS, 256, 0, stream>>>(c, y, partials);
    bpmll_reduce_kernel<<<1, 256, 0, stream>>>(partials, out);
}

// Round 6
// 136.713 us; speedup vs baseline: 1.0537x; 1.0537x over previous
//
#include <hip/hip_runtime.h>

// BPMLL loss, B=16384 rows, L=1024 cols, f32 in, scalar f32 out.
// Per row: pos = sum y*exp(-c); neg = sum (1-y)*exp(c);
// loss = pos*neg/(sum_y*(L-sum_y)); out = mean over rows.
//
// R1/R2/R4: three structurally different kernels all at ~43us = 134MB /
// 3.12 TB/s read-only (half HBM, half L3-hit). Wave count, block count and
// per-wave MLP all neutral -> service-rate ceiling suspected (m13's 6.29TB/s
// copy = ~3.15 TB/s per direction). This round (R5 = R4 with compile fix:
// __builtin_nontemporal_load needs clang ext_vector_type, not HIP structs):
//  - nontemporal loads (nt bit): skip cache allocation on the fill path in
//    case read-miss-allocate is the throttle.
//  - persistent co-resident blocks (512), 8 contiguous rows/wave, register
//    double-buffer prefetch: zero wave churn, 2048 long sequential streams.

#define NROWS 16384
#define NCOLS 1024
#define WPB 4
#define NBLOCKS 512                        // 2 blocks/CU, co-resident
#define ROWS_PER_WAVE (NROWS / (NBLOCKS * WPB))  // 8

typedef float vf4 __attribute__((ext_vector_type(4)));
typedef int vi4 __attribute__((ext_vector_type(4)));

__device__ __forceinline__ void elem(float cv, int yv,
                                     float& pos, float& neg, float& cnt) {
    float t = __expf(yv ? -cv : cv);   // one transcendental per element
    pos += yv ? t : 0.f;
    neg += yv ? 0.f : t;
    cnt += (float)yv;
}

__device__ __forceinline__ void consume4(const vf4& cv, const vi4& yv,
                                         float& pos, float& neg, float& cnt) {
    elem(cv.x, yv.x, pos, neg, cnt);
    elem(cv.y, yv.y, pos, neg, cnt);
    elem(cv.z, yv.z, pos, neg, cnt);
    elem(cv.w, yv.w, pos, neg, cnt);
}

__device__ __forceinline__ float row_finish(float pos, float neg, float cnt) {
#pragma unroll
    for (int off = 1; off < 64; off <<= 1) {
        pos += __shfl_xor(pos, off);
        neg += __shfl_xor(neg, off);
        cnt += __shfl_xor(cnt, off);
    }
    return (pos * neg) / (cnt * ((float)NCOLS - cnt));  // BIAS=(1,1)
}

__global__ __launch_bounds__(256, 2) void bpmll_rows_kernel(
    const float* __restrict__ c, const int* __restrict__ y,
    float* __restrict__ partials) {
    const int wave = threadIdx.x >> 6;
    const int lane = threadIdx.x & 63;
    const int gw = blockIdx.x * WPB + wave;        // 0..2047
    const int row0 = gw * ROWS_PER_WAVE;           // 8 contiguous rows/wave

    const vf4* __restrict__ cp = (const vf4*)(c + (size_t)row0 * NCOLS);
    const vi4* __restrict__ yp = (const vi4*)(y + (size_t)row0 * NCOLS);
    // row stride = 256 vf4 / vi4

    vf4 cbuf[2][4];
    vi4 ybuf[2][4];

    // Prime the pipeline: row 0 into buffer 0 (nontemporal).
#pragma unroll
    for (int i = 0; i < 4; ++i)
        cbuf[0][i] = __builtin_nontemporal_load(&cp[lane + 64 * i]);
#pragma unroll
    for (int i = 0; i < 4; ++i)
        ybuf[0][i] = __builtin_nontemporal_load(&yp[lane + 64 * i]);

    float wave_loss = 0.f;
#pragma unroll
    for (int r = 0; r < ROWS_PER_WAVE; ++r) {
        const int cur = r & 1, nxt = cur ^ 1;
        if (r < ROWS_PER_WAVE - 1) {  // prefetch next row while consuming
            const vf4* cn = cp + (size_t)(r + 1) * (NCOLS / 4);
            const vi4* yn = yp + (size_t)(r + 1) * (NCOLS / 4);
#pragma unroll
            for (int i = 0; i < 4; ++i)
                cbuf[nxt][i] = __builtin_nontemporal_load(&cn[lane + 64 * i]);
#pragma unroll
            for (int i = 0; i < 4; ++i)
                ybuf[nxt][i] = __builtin_nontemporal_load(&yn[lane + 64 * i]);
        }
        float pos = 0.f, neg = 0.f, cnt = 0.f;
#pragma unroll
        for (int i = 0; i < 4; ++i)
            consume4(cbuf[cur][i], ybuf[cur][i], pos, neg, cnt);
        wave_loss += row_finish(pos, neg, cnt);
    }

    __shared__ float acc[WPB];
    if (lane == 0) acc[wave] = wave_loss;
    __syncthreads();
    if (threadIdx.x == 0) {
        partials[blockIdx.x] =
            (acc[0] + acc[1] + acc[2] + acc[3]) * (1.0f / (float)NROWS);
    }
}

__global__ __launch_bounds__(256) void bpmll_reduce_kernel(
    const float* __restrict__ partials, float* __restrict__ out) {
    // 512 partials, 256 threads -> two floats per thread.
    float s = partials[threadIdx.x] + partials[threadIdx.x + 256];
#pragma unroll
    for (int off = 1; off < 64; off <<= 1) s += __shfl_xor(s, off);

    __shared__ float smem[4];
    const int lane = threadIdx.x & 63;
    const int wave = threadIdx.x >> 6;
    if (lane == 0) smem[wave] = s;
    __syncthreads();
    if (threadIdx.x == 0) out[0] = smem[0] + smem[1] + smem[2] + smem[3];
}

extern "C" void kernel_launch(void* const* d_in, const int* in_sizes, int n_in,
                              void* d_out, int out_size, void* d_ws, size_t ws_size,
                              hipStream_t stream) {
    const float* c = (const float*)d_in[0];
    const int* y = (const int*)d_in[1];
    float* partials = (float*)d_ws;   // NBLOCKS floats = 2 KiB scratch
    float* out = (float*)d_out;

    bpmll_rows_kernel<<<NBLOCKS, 256, 0, stream>>>(c, y, partials);
    bpmll_reduce_kernel<<<1, 256, 0, stream>>>(partials, out);
}